// Round 8
// baseline (2207.492 us; speedup 1.0000x reference)
//
#include <hip/hip_runtime.h>
#include <hip/hip_bf16.h>

#define BB 64
#define TT 512
#define HH 256
#define EE 128
#define VV 32000
#define SS 128
#define LL 16

typedef __attribute__((ext_vector_type(8))) short bf16x8;
typedef __attribute__((ext_vector_type(4))) float f32x4;

static __device__ __forceinline__ unsigned short f2bf(float x) {
    unsigned int u = __float_as_uint(x);
    unsigned int r = (u + 0x7fffu + ((u >> 16) & 1u)) >> 16;
    return (unsigned short)r;
}

// tanh(x) = 1 - 2/(exp2(x*2*log2e)+1)
static __device__ __forceinline__ float ftanh(float x) {
    float y = __builtin_amdgcn_exp2f(x * 2.885390082f);
    return 1.f - 2.f * __builtin_amdgcn_rcpf(y + 1.f);
}

// ================= body: pre {hW, prep_b, embed} =================
__device__ __forceinline__ void pre_body(int blk, int tid,
                                         const float* __restrict__ last_hidden,
                                         const float* __restrict__ attn_W,
                                         const float* __restrict__ attn_b,
                                         const int* __restrict__ z_tm1,
                                         const float* __restrict__ emb_W,
                                         const float* __restrict__ ctrl_W,
                                         const float* __restrict__ ctrl_b,
                                         float* __restrict__ hW,
                                         float* __restrict__ embed,
                                         unsigned short* __restrict__ Bs,
                                         float* sh) {
    if (blk < 64) {
        int b = blk, h = tid;
        sh[h] = last_hidden[b * HH + h];
        __syncthreads();
        const float4* wrow = (const float4*)(attn_W + (size_t)h * (2 * HH));
        float acc = attn_b[h];
        for (int k4 = 0; k4 < HH / 4; ++k4) {
            float4 w = wrow[k4];
            acc += sh[k4*4+0]*w.x + sh[k4*4+1]*w.y + sh[k4*4+2]*w.z + sh[k4*4+3]*w.w;
        }
        hW[b * HH + h] = acc;
    } else if (blk < 96) {
        int idx = (blk - 64) * 256 + tid;  // 8192 total
        int lane = idx & 63;
        int gt = (idx >> 6) & 15;
        int ks = idx >> 10;
        int col = gt * 16 + (lane & 15);
        int k0 = ks * 32 + (lane >> 4) * 8;
        const float* src = attn_W + (size_t)col * (2 * HH) + HH + k0;
        unsigned int p0 = f2bf(src[0]) | ((unsigned int)f2bf(src[1]) << 16);
        unsigned int p1 = f2bf(src[2]) | ((unsigned int)f2bf(src[3]) << 16);
        unsigned int p2 = f2bf(src[4]) | ((unsigned int)f2bf(src[5]) << 16);
        unsigned int p3 = f2bf(src[6]) | ((unsigned int)f2bf(src[7]) << 16);
        *(uint4*)(Bs + (size_t)idx * 8) = make_uint4(p0, p1, p2, p3);
    } else {
        int b = blk - 96;
        if (tid < EE) sh[tid] = emb_W[(size_t)z_tm1[b] * EE + tid];
        __syncthreads();
        if (tid < EE) {
            const float4* wrow = (const float4*)(ctrl_W + (size_t)tid * EE);
            float acc = ctrl_b[tid] + sh[tid];
            for (int k4 = 0; k4 < EE / 4; ++k4) {
                float4 w = wrow[k4];
                acc += sh[k4*4+0]*w.x + sh[k4*4+1]*w.y + sh[k4*4+2]*w.z + sh[k4*4+3]*w.w;
            }
            embed[b * EE + tid] = acc;
        }
    }
}

__global__ __launch_bounds__(256) void k_pre(const float* __restrict__ last_hidden,
                                             const float* __restrict__ attn_W,
                                             const float* __restrict__ attn_b,
                                             const int* __restrict__ z_tm1,
                                             const float* __restrict__ emb_W,
                                             const float* __restrict__ ctrl_W,
                                             const float* __restrict__ ctrl_b,
                                             float* __restrict__ hW,
                                             float* __restrict__ embed,
                                             unsigned short* __restrict__ Bs) {
    __shared__ float sh[HH];
    pre_body(blockIdx.x, threadIdx.x, last_hidden, attn_W, attn_b, z_tm1, emb_W,
             ctrl_W, ctrl_b, hW, embed, Bs, sh);
}

__global__ __launch_bounds__(256) void k_pre_x16(const float* __restrict__ last_hidden,
                                                 const float* __restrict__ attn_W,
                                                 const float* __restrict__ attn_b,
                                                 const int* __restrict__ z_tm1,
                                                 const float* __restrict__ emb_W,
                                                 const float* __restrict__ ctrl_W,
                                                 const float* __restrict__ ctrl_b,
                                                 float* __restrict__ hW,
                                                 float* __restrict__ embed,
                                                 unsigned short* __restrict__ Bs) {
    __shared__ float sh[HH];
    for (int rep = 0; rep < 16; ++rep) {
        __syncthreads();
        pre_body(blockIdx.x, threadIdx.x, last_hidden, attn_W, attn_b, z_tm1, emb_W,
                 ctrl_W, ctrl_b, hW, embed, Bs, sh);
    }
}

// ================= body: scores via bf16 MFMA -> scoresT[b][t] =================
__device__ __forceinline__ void scores_body(int i0, int tid,
                                            const float* __restrict__ enc,
                                            const unsigned short* __restrict__ Bs,
                                            const float* __restrict__ attn_v,
                                            const float* __restrict__ hW,
                                            float* __restrict__ scoresT,
                                            unsigned char* Abuf, float* scpart) {
    const float4* src = (const float4*)(enc + (size_t)i0 * HH);
#pragma unroll
    for (int it = 0; it < 4; ++it) {
        int c = tid + it * 256;
        int row = c >> 5;
        int kc = c & 31;
        float4 f0 = src[c * 2];
        float4 f1 = src[c * 2 + 1];
        unsigned int p0 = f2bf(f0.x) | ((unsigned int)f2bf(f0.y) << 16);
        unsigned int p1 = f2bf(f0.z) | ((unsigned int)f2bf(f0.w) << 16);
        unsigned int p2 = f2bf(f1.x) | ((unsigned int)f2bf(f1.y) << 16);
        unsigned int p3 = f2bf(f1.z) | ((unsigned int)f2bf(f1.w) << 16);
        int addr = (row * 512 + kc * 16) ^ ((row & 7) << 4);
        *(uint4*)(Abuf + addr) = make_uint4(p0, p1, p2, p3);
    }
    __syncthreads();

    int wv = tid >> 6, lane = tid & 63;
    int lrow = lane & 15, q = lane >> 4;

    f32x4 acc[2][4];
#pragma unroll
    for (int rt = 0; rt < 2; ++rt)
#pragma unroll
        for (int ct = 0; ct < 4; ++ct) acc[rt][ct] = (f32x4){0.f, 0.f, 0.f, 0.f};

    const bf16x8* BsV = (const bf16x8*)Bs;
    for (int ks = 0; ks < 8; ++ks) {
        bf16x8 bfr[4];
        const bf16x8* bsrc = BsV + ((size_t)(ks * 16 + wv * 4) * 64 + lane);
#pragma unroll
        for (int ct = 0; ct < 4; ++ct) bfr[ct] = bsrc[ct * 64];
        bf16x8 afr[2];
#pragma unroll
        for (int rt = 0; rt < 2; ++rt) {
            int arow = rt * 16 + lrow;
            int abyte = (arow * 512 + ks * 64 + q * 16) ^ ((arow & 7) << 4);
            afr[rt] = *(const bf16x8*)(Abuf + abyte);
        }
#pragma unroll
        for (int rt = 0; rt < 2; ++rt)
#pragma unroll
            for (int ct = 0; ct < 4; ++ct)
                acc[rt][ct] = __builtin_amdgcn_mfma_f32_16x16x32_bf16(afr[rt], bfr[ct], acc[rt][ct], 0, 0, 0);
    }

    float vvv[4];
#pragma unroll
    for (int ct = 0; ct < 4; ++ct) vvv[ct] = attn_v[wv * 64 + ct * 16 + lrow];

#pragma unroll
    for (int rt = 0; rt < 2; ++rt) {
        float ps[4];
#pragma unroll
        for (int r = 0; r < 4; ++r) {
            int i = i0 + rt * 16 + q * 4 + r;
            int b = i & (BB - 1);
            const float* hwb = hW + (size_t)b * HH + wv * 64 + lrow;
            float s = 0.f;
#pragma unroll
            for (int ct = 0; ct < 4; ++ct)
                s += vvv[ct] * ftanh(acc[rt][ct][r] + hwb[ct * 16]);
#pragma unroll
            for (int off = 1; off < 16; off <<= 1) s += __shfl_xor(s, off, 64);
            ps[r] = s;
        }
        if (lrow == 0) {
#pragma unroll
            for (int r = 0; r < 4; ++r) scpart[wv * 32 + rt * 16 + q * 4 + r] = ps[r];
        }
    }
    __syncthreads();
    if (tid < 32) {
        float s = scpart[tid] + scpart[32 + tid] + scpart[64 + tid] + scpart[96 + tid];
        int i = i0 + tid;                       // i = t*B + b
        scoresT[(i & 63) * TT + (i >> 6)] = s;  // [b][t]
    }
}

__global__ __launch_bounds__(256) void k_scores_mfma(const float* __restrict__ enc,
                                                     const unsigned short* __restrict__ Bs,
                                                     const float* __restrict__ attn_v,
                                                     const float* __restrict__ hW,
                                                     float* __restrict__ scoresT) {
    __shared__ uint4 AbufV[1024];
    __shared__ float scpart[128];
    scores_body(blockIdx.x * 32, threadIdx.x, enc, Bs, attn_v, hW, scoresT,
                (unsigned char*)AbufV, scpart);
}

__global__ __launch_bounds__(256) void k_scores_x16(const float* __restrict__ enc,
                                                    const unsigned short* __restrict__ Bs,
                                                    const float* __restrict__ attn_v,
                                                    const float* __restrict__ hW,
                                                    float* __restrict__ scoresT) {
    __shared__ uint4 AbufV[1024];
    __shared__ float scpart[128];
    for (int rep = 0; rep < 16; ++rep) {
        __syncthreads();
        scores_body(blockIdx.x * 32, threadIdx.x, enc, Bs, attn_v, hW, scoresT,
                    (unsigned char*)AbufV, scpart);
    }
}

// ================= body: ctx partials =================
// smem carve: red[8]@0, wloc[32]@8, part[1024]@40
__device__ __forceinline__ void ctx_body(int bx, int tid,
                                         const float* __restrict__ enc,
                                         const float* __restrict__ scoresT,
                                         float* __restrict__ partial,
                                         float* smem) {
    float* red = smem;
    float* wloc = smem + 8;
    float* part = smem + 40;
    int c = bx >> 6, b = bx & 63;
    int lane = tid & 63, wv = tid >> 6;

    float s0 = scoresT[b * TT + 2 * tid];
    float s1 = scoresT[b * TT + 2 * tid + 1];
    float mx = fmaxf(s0, s1);
#pragma unroll
    for (int off = 32; off; off >>= 1) mx = fmaxf(mx, __shfl_xor(mx, off, 64));
    if (lane == 0) red[wv] = mx;
    __syncthreads();
    float m = fmaxf(fmaxf(red[0], red[1]), fmaxf(red[2], red[3]));
    float e0 = expf(s0 - m), e1 = expf(s1 - m);
    float sm = e0 + e1;
#pragma unroll
    for (int off = 32; off; off >>= 1) sm += __shfl_xor(sm, off, 64);
    if (lane == 0) red[4 + wv] = sm;
    __syncthreads();
    float inv = 1.f / (red[4] + red[5] + red[6] + red[7]);
    if (tid < 32) wloc[tid] = expf(scoresT[b * TT + c * 32 + tid] - m) * inv;
    __syncthreads();

    int h4 = tid & 63, g = tid >> 6;
    f32x4 c4 = {0.f, 0.f, 0.f, 0.f};
    const f32x4* enc4 = (const f32x4*)enc;
    size_t base = ((size_t)(c * 32 + g * 8) * BB + b) * 64 + h4;
#pragma unroll
    for (int i = 0; i < 8; ++i) {
        float wt = wloc[g * 8 + i];
        f32x4 v = enc4[base + (size_t)i * BB * 64];
        c4.x += wt * v.x; c4.y += wt * v.y; c4.z += wt * v.z; c4.w += wt * v.w;
    }
    *(f32x4*)&part[g * 1024 / 4 + h4 * 4] = c4;
    __syncthreads();
    if (tid < 64) {
        f32x4 a0 = *(const f32x4*)&part[0 * 256 + tid * 4];
        f32x4 a1 = *(const f32x4*)&part[1 * 256 + tid * 4];
        f32x4 a2 = *(const f32x4*)&part[2 * 256 + tid * 4];
        f32x4 a3 = *(const f32x4*)&part[3 * 256 + tid * 4];
        f32x4 t4;
        t4.x = a0.x + a1.x + a2.x + a3.x;
        t4.y = a0.y + a1.y + a2.y + a3.y;
        t4.z = a0.z + a1.z + a2.z + a3.z;
        t4.w = a0.w + a1.w + a2.w + a3.w;
        *(f32x4*)&partial[((size_t)c * BB + b) * HH + tid * 4] = t4;
    }
}

__global__ __launch_bounds__(256) void k_ctx(const float* __restrict__ enc,
                                             const float* __restrict__ scoresT,
                                             float* __restrict__ partial) {
    __shared__ __align__(16) float smem[1064];
    ctx_body(blockIdx.x, threadIdx.x, enc, scoresT, partial, smem);
}

__global__ __launch_bounds__(256) void k_ctx_x16(const float* __restrict__ enc,
                                                 const float* __restrict__ scoresT,
                                                 float* __restrict__ partial) {
    __shared__ __align__(16) float smem[1064];
    for (int rep = 0; rep < 16; ++rep) {
        __syncthreads();
        ctx_body(blockIdx.x, threadIdx.x, enc, scoresT, partial, smem);
    }
}

// ================= body: ffnn (partial-sum + hidden + gen + probas stats) =================
// smem carve: part[1024]@0, fin[640]@1024, hid[256]@1664, genl[128]@1920,
//             red[128]@2048, slotL[2048 ints]@2176. total 4224 floats.
__device__ __forceinline__ void ffnn_body(int b, int tid,
                                          const float* __restrict__ partial,
                                          const float* __restrict__ embed,
                                          const float* __restrict__ last_hidden,
                                          const float* __restrict__ Whid,
                                          const float* __restrict__ bhid,
                                          const float* __restrict__ Wout,
                                          const float* __restrict__ bout,
                                          const int* __restrict__ slot,
                                          float* __restrict__ out_hidden,
                                          float* __restrict__ gen,
                                          float* __restrict__ pvals,
                                          float* __restrict__ pbase,
                                          float* smem) {
    float* part = smem;
    float* fin  = smem + 1024;
    float* hid  = smem + 1664;
    float* genl = smem + 1920;
    float* red  = smem + 2048;
    int* slotL  = (int*)(smem + 2176);
    int lane = tid & 63, wv = tid >> 6;

    slotL[tid] = slot[tid];
    slotL[tid + 1024] = slot[tid + 1024];

    // phase A: sum 16 partials
    {
        int h = tid & 255, pc = tid >> 8;
        float a = 0.f;
#pragma unroll
        for (int j = 0; j < 4; ++j)
            a += partial[((size_t)(pc * 4 + j) * BB + b) * HH + h];
        part[pc * 256 + h] = a;
    }
    __syncthreads();
    if (tid < 256) fin[EE + tid] = part[tid] + part[256 + tid] + part[512 + tid] + part[768 + tid];
    else if (tid < 384) fin[tid - 256] = embed[b * EE + (tid - 256)];
    else if (tid < 640) fin[EE + HH + (tid - 384)] = last_hidden[b * HH + (tid - 384)];
    __syncthreads();

    // phase B: hidden
    {
        int o = tid & 255, kh = tid >> 8;
        const f32x4* wrow = (const f32x4*)(Whid + (size_t)o * (2 * HH + EE)) + kh * 40;
        const float* fb = fin + kh * 160;
        float a2 = 0.f;
#pragma unroll 8
        for (int k4 = 0; k4 < 40; ++k4) {
            f32x4 ww = wrow[k4];
            a2 += fb[k4*4+0]*ww.x + fb[k4*4+1]*ww.y + fb[k4*4+2]*ww.z + fb[k4*4+3]*ww.w;
        }
        part[kh * 256 + o] = a2;
    }
    __syncthreads();
    if (tid < HH) {
        float hv = fmaxf(part[tid] + part[256 + tid] + part[512 + tid] + part[768 + tid] + bhid[tid], 0.f);
        hid[tid] = hv;
        out_hidden[(size_t)b * HH + tid] = hv;
    }
    __syncthreads();

    // phase C: gen
    {
        int o = tid & 127, q8 = tid >> 7;
        const f32x4* wrow = (const f32x4*)(Wout + (size_t)o * HH) + q8 * 8;
        const float* hb = hid + q8 * 32;
        float a3 = 0.f;
#pragma unroll
        for (int k4 = 0; k4 < 8; ++k4) {
            f32x4 ww = wrow[k4];
            a3 += hb[k4*4+0]*ww.x + hb[k4*4+1]*ww.y + hb[k4*4+2]*ww.z + hb[k4*4+3]*ww.w;
        }
        part[q8 * 128 + o] = a3;
    }
    __syncthreads();
    if (tid < SS) {
        float gv = bout[tid];
#pragma unroll
        for (int j = 0; j < 8; ++j) gv += part[j * 128 + tid];
        gv = fmaxf(gv, 0.f);
        genl[tid] = gv;
        gen[(size_t)b * SS + tid] = gv;
    }
    __syncthreads();

    // phase D: probas stats
    {
        int sA = tid & 127, lA = tid >> 7, lB = lA + 8;
        float mgA, mgB;
        bool fA, fB;
        {
            int c = slotL[lA * 128 + sA];
            float sum = 0.f; int fi = SS;
            for (int s2 = 0; s2 < SS; ++s2) {
                if (slotL[lA * 128 + s2] == c) { sum += genl[s2]; if (s2 < fi) fi = s2; }
            }
            mgA = -0.01f + sum; fA = (fi == sA);
        }
        {
            int c = slotL[lB * 128 + sA];
            float sum = 0.f; int fi = SS;
            for (int s2 = 0; s2 < SS; ++s2) {
                if (slotL[lB * 128 + s2] == c) { sum += genl[s2]; if (s2 < fi) fi = s2; }
            }
            mgB = -0.01f + sum; fB = (fi == sA);
        }
        float mA = mgA, mB = mgB;
#pragma unroll
        for (int off = 32; off; off >>= 1) {
            mA = fmaxf(mA, __shfl_xor(mA, off, 64));
            mB = fmaxf(mB, __shfl_xor(mB, off, 64));
        }
        if (lane == 0) { red[wv] = mA; red[16 + wv] = mB; }
        __syncthreads();
        float MA = fmaxf(red[2 * lA], red[2 * lA + 1]);
        float MB = fmaxf(red[16 + 2 * lA], red[16 + 2 * lA + 1]);
        float eA = fA ? expf(mgA - MA) : 0.f;
        float eB = fB ? expf(mgB - MB) : 0.f;
        float cA = fA ? 1.f : 0.f, cB = fB ? 1.f : 0.f;
        float s1 = eA, s2v = cA, s3 = eB, s4 = cB;
#pragma unroll
        for (int off = 32; off; off >>= 1) {
            s1 += __shfl_xor(s1, off, 64);
            s2v += __shfl_xor(s2v, off, 64);
            s3 += __shfl_xor(s3, off, 64);
            s4 += __shfl_xor(s4, off, 64);
        }
        if (lane == 0) { red[32 + wv] = s1; red[48 + wv] = s2v; red[64 + wv] = s3; red[80 + wv] = s4; }
        __syncthreads();
        float sumA = red[32 + 2 * lA] + red[32 + 2 * lA + 1];
        float cntA = red[48 + 2 * lA] + red[48 + 2 * lA + 1];
        float sumB = red[64 + 2 * lA] + red[64 + 2 * lA + 1];
        float cntB = red[80 + 2 * lA] + red[80 + 2 * lA + 1];
        float baseA = expf(-0.01f - MA);
        float invA = 1.f / (((float)VV - cntA) * baseA + sumA);
        float baseB = expf(-0.01f - MB);
        float invB = 1.f / (((float)VV - cntB) * baseB + sumB);
        pvals[((size_t)b * LL + lA) * SS + sA] = fA ? expf(mgA - MA) * invA : -1.f;
        pvals[((size_t)b * LL + lB) * SS + sA] = fB ? expf(mgB - MB) * invB : -1.f;
        if (sA == 0) {
            pbase[b * LL + lA] = baseA * invA;
            pbase[b * LL + lB] = baseB * invB;
        }
    }
    __syncthreads();
}

__global__ __launch_bounds__(1024) void k_ffnn(const float* __restrict__ partial,
                                               const float* __restrict__ embed,
                                               const float* __restrict__ last_hidden,
                                               const float* __restrict__ Whid,
                                               const float* __restrict__ bhid,
                                               const float* __restrict__ Wout,
                                               const float* __restrict__ bout,
                                               const int* __restrict__ slot,
                                               float* __restrict__ out_hidden,
                                               float* __restrict__ gen,
                                               float* __restrict__ pvals,
                                               float* __restrict__ pbase) {
    __shared__ __align__(16) float smem[4224];
    ffnn_body(blockIdx.x, threadIdx.x, partial, embed, last_hidden, Whid, bhid,
              Wout, bout, slot, out_hidden, gen, pvals, pbase, smem);
}

__global__ __launch_bounds__(1024) void k_ffnn_x48(const float* __restrict__ partial,
                                                   const float* __restrict__ embed,
                                                   const float* __restrict__ last_hidden,
                                                   const float* __restrict__ Whid,
                                                   const float* __restrict__ bhid,
                                                   const float* __restrict__ Wout,
                                                   const float* __restrict__ bout,
                                                   const int* __restrict__ slot,
                                                   float* __restrict__ out_hidden,
                                                   float* __restrict__ gen,
                                                   float* __restrict__ pvals,
                                                   float* __restrict__ pbase) {
    __shared__ __align__(16) float smem[4224];
    for (int rep = 0; rep < 48; ++rep) {
        __syncthreads();
        ffnn_body(blockIdx.x, threadIdx.x, partial, embed, last_hidden, Whid, bhid,
                  Wout, bout, slot, out_hidden, gen, pvals, pbase, smem);
    }
}

// ================= body: fill =================
__device__ __forceinline__ void fill_body(int bx, int tid,
                                          const int* __restrict__ slot,
                                          const float* __restrict__ pvals,
                                          const float* __restrict__ pbase,
                                          float* __restrict__ out,
                                          float* pv, int* cls) {
    int row = bx >> 1, half = bx & 1;
    int l = row >> 6, b = row & 63;
    if (tid < SS) {
        pv[tid] = pvals[((size_t)b * LL + l) * SS + tid];
        cls[tid] = slot[l * SS + tid];
    }
    float pb = pbase[b * LL + l];
    float* rowp = out + BB * HH + ((size_t)(l * BB + b)) * VV;
    float4 p4 = make_float4(pb, pb, pb, pb);
    float4* row4 = (float4*)rowp + half * (VV / 8);
#pragma unroll 4
    for (int idx = tid; idx < VV / 8; idx += 256) row4[idx] = p4;
    __syncthreads();
    if (tid < SS && pv[tid] >= 0.f) {
        int c = cls[tid];
        int lo = half * (VV / 2);
        if (c >= lo && c < lo + VV / 2) rowp[c] = pv[tid];
    }
}

__global__ __launch_bounds__(256) void k_fill(const int* __restrict__ slot,
                                              const float* __restrict__ pvals,
                                              const float* __restrict__ pbase,
                                              float* __restrict__ out) {
    __shared__ float pv[SS];
    __shared__ int cls[SS];
    fill_body(blockIdx.x, threadIdx.x, slot, pvals, pbase, out, pv, cls);
}

__global__ __launch_bounds__(256) void k_fill_x6(const int* __restrict__ slot,
                                                 const float* __restrict__ pvals,
                                                 const float* __restrict__ pbase,
                                                 float* __restrict__ out) {
    __shared__ float pv[SS];
    __shared__ int cls[SS];
    for (int rep = 0; rep < 6; ++rep) {
        __syncthreads();
        fill_body(blockIdx.x, threadIdx.x, slot, pvals, pbase, out, pv, cls);
    }
}

extern "C" void kernel_launch(void* const* d_in, const int* in_sizes, int n_in,
                              void* d_out, int out_size, void* d_ws, size_t ws_size,
                              hipStream_t stream) {
    const float* u_enc       = (const float*)d_in[0];
    const float* last_hidden = (const float*)d_in[1];
    const int*   z_tm1       = (const int*)d_in[2];
    const int*   slot        = (const int*)d_in[3];
    const float* emb_W       = (const float*)d_in[4];
    const float* ctrl_W      = (const float*)d_in[5];
    const float* ctrl_b      = (const float*)d_in[6];
    const float* attn_W      = (const float*)d_in[7];
    const float* attn_b      = (const float*)d_in[8];
    const float* attn_v      = (const float*)d_in[9];
    const float* Whid        = (const float*)d_in[10];
    const float* bhid        = (const float*)d_in[11];
    const float* Wout        = (const float*)d_in[12];
    const float* bout        = (const float*)d_in[13];
    float* out = (float*)d_out;
    float* ws = (float*)d_ws;

    float* scoresT = ws;             // 32768 ([b][t])
    float* hW      = ws + 32768;     // 16384
    float* embed   = ws + 49152;     // 8192
    float* gen     = ws + 57344;     // 8192
    unsigned short* Bs = (unsigned short*)(ws + 65536);  // 65536 bf16
    float* pvals   = ws + 98304;     // 131072
    float* pbase   = ws + 229376;    // 1024
    float* partial = ws + 230400;    // 262144

    // ---- real pipeline (identical to round 7) ----
    k_pre<<<160, 256, 0, stream>>>(last_hidden, attn_W, attn_b, z_tm1, emb_W, ctrl_W,
                                   ctrl_b, hW, embed, Bs);
    k_scores_mfma<<<(TT * BB) / 32, 256, 0, stream>>>(u_enc, Bs, attn_v, hW, scoresT);
    k_ctx<<<16 * BB, 256, 0, stream>>>(u_enc, scoresT, partial);
    k_ffnn<<<BB, 1024, 0, stream>>>(partial, embed, last_hidden, Whid, bhid,
                                    Wout, bout, slot, out, gen, pvals, pbase);
    k_fill<<<LL * BB * 2, 256, 0, stream>>>(slot, pvals, pbase, out);

    // ---- instruments: scratch-only, deterministic, run after real pipeline ----
    if (ws_size >= ((size_t)200 << 20)) {
        float* base2 = ws + 2097152;           // 8 MB offset
        float* hW2      = base2;               // 16384
        float* embed2   = base2 + 16384;       // 8192
        unsigned short* Bs2 = (unsigned short*)(base2 + 24576);  // 65536 bf16
        float* scoresT2 = base2 + 57344;       // 32768
        float* partial2 = base2 + 90112;       // 262144
        float* gen2     = base2 + 352256;      // 8192
        float* hid2     = base2 + 360448;      // 16384
        float* pvals2   = base2 + 376832;      // 131072
        float* pbase2   = base2 + 507904;      // 1024
        float* fillout2 = ws + 12582912;       // 48 MB offset, 131.2 MB used

        k_pre_x16<<<160, 256, 0, stream>>>(last_hidden, attn_W, attn_b, z_tm1, emb_W,
                                           ctrl_W, ctrl_b, hW2, embed2, Bs2);
        k_scores_x16<<<(TT * BB) / 32, 256, 0, stream>>>(u_enc, Bs, attn_v, hW, scoresT2);
        k_ctx_x16<<<16 * BB, 256, 0, stream>>>(u_enc, scoresT, partial2);
        k_ffnn_x48<<<BB, 1024, 0, stream>>>(partial, embed, last_hidden, Whid, bhid,
                                            Wout, bout, slot, hid2, gen2, pvals2, pbase2);
        k_fill_x6<<<LL * BB * 2, 256, 0, stream>>>(slot, pvals, pbase, fillout2);
    }
}

// Round 9
// 89.273 us; speedup vs baseline: 24.7275x; 24.7275x over previous
//
#include <hip/hip_runtime.h>
#include <hip/hip_bf16.h>

#define BB 64
#define TT 512
#define HH 256
#define EE 128
#define VV 32000
#define SS 128
#define LL 16

typedef __attribute__((ext_vector_type(8))) short bf16x8;
typedef __attribute__((ext_vector_type(4))) float f32x4;

static __device__ __forceinline__ unsigned short f2bf(float x) {
    unsigned int u = __float_as_uint(x);
    unsigned int r = (u + 0x7fffu + ((u >> 16) & 1u)) >> 16;
    return (unsigned short)r;
}

// tanh(x) = 1 - 2/(exp2(x*2*log2e)+1)
static __device__ __forceinline__ float ftanh(float x) {
    float y = __builtin_amdgcn_exp2f(x * 2.885390082f);
    return 1.f - 2.f * __builtin_amdgcn_rcpf(y + 1.f);
}

// ================= K1: {hW, prep_b, embed, slot-firstidx} by blockIdx =================
__global__ __launch_bounds__(256) void k_pre(const float* __restrict__ last_hidden,
                                             const float* __restrict__ attn_W,
                                             const float* __restrict__ attn_b,
                                             const int* __restrict__ z_tm1,
                                             const float* __restrict__ emb_W,
                                             const float* __restrict__ ctrl_W,
                                             const float* __restrict__ ctrl_b,
                                             const int* __restrict__ slot,
                                             float* __restrict__ hW,
                                             float* __restrict__ embed,
                                             unsigned short* __restrict__ Bs,
                                             int* __restrict__ fidx) {
    __shared__ float sh[HH];
    __shared__ int shi[256];
    int blk = blockIdx.x;
    int tid = threadIdx.x;
    if (blk < 64) {
        int b = blk, h = tid;
        sh[h] = last_hidden[b * HH + h];
        __syncthreads();
        const float4* wrow = (const float4*)(attn_W + (size_t)h * (2 * HH));
        float a0 = 0.f, a1 = 0.f, a2 = 0.f, a3 = 0.f;
        for (int k4 = 0; k4 < HH / 4; k4 += 4) {
            float4 w0 = wrow[k4], w1 = wrow[k4+1], w2 = wrow[k4+2], w3 = wrow[k4+3];
            a0 += sh[k4*4+ 0]*w0.x + sh[k4*4+ 1]*w0.y + sh[k4*4+ 2]*w0.z + sh[k4*4+ 3]*w0.w;
            a1 += sh[k4*4+ 4]*w1.x + sh[k4*4+ 5]*w1.y + sh[k4*4+ 6]*w1.z + sh[k4*4+ 7]*w1.w;
            a2 += sh[k4*4+ 8]*w2.x + sh[k4*4+ 9]*w2.y + sh[k4*4+10]*w2.z + sh[k4*4+11]*w2.w;
            a3 += sh[k4*4+12]*w3.x + sh[k4*4+13]*w3.y + sh[k4*4+14]*w3.z + sh[k4*4+15]*w3.w;
        }
        hW[b * HH + h] = attn_b[h] + ((a0 + a1) + (a2 + a3));
    } else if (blk < 96) {
        // Bs layout: [kstep 0..7][tile 0..15][lane 0..63][8 bf16]
        int idx = (blk - 64) * 256 + tid;  // 8192 total
        int lane = idx & 63;
        int gt = (idx >> 6) & 15;
        int ks = idx >> 10;
        int col = gt * 16 + (lane & 15);
        int k0 = ks * 32 + (lane >> 4) * 8;
        const float* src = attn_W + (size_t)col * (2 * HH) + HH + k0;
        unsigned int p0 = f2bf(src[0]) | ((unsigned int)f2bf(src[1]) << 16);
        unsigned int p1 = f2bf(src[2]) | ((unsigned int)f2bf(src[3]) << 16);
        unsigned int p2 = f2bf(src[4]) | ((unsigned int)f2bf(src[5]) << 16);
        unsigned int p3 = f2bf(src[6]) | ((unsigned int)f2bf(src[7]) << 16);
        *(uint4*)(Bs + (size_t)idx * 8) = make_uint4(p0, p1, p2, p3);
    } else if (blk < 160) {
        int b = blk - 96;
        if (tid < EE) sh[tid] = emb_W[(size_t)z_tm1[b] * EE + tid];
        __syncthreads();
        if (tid < EE) {
            const float4* wrow = (const float4*)(ctrl_W + (size_t)tid * EE);
            float a0 = 0.f, a1 = 0.f;
            for (int k4 = 0; k4 < EE / 4; k4 += 2) {
                float4 w0 = wrow[k4], w1 = wrow[k4+1];
                a0 += sh[k4*4+0]*w0.x + sh[k4*4+1]*w0.y + sh[k4*4+2]*w0.z + sh[k4*4+3]*w0.w;
                a1 += sh[k4*4+4]*w1.x + sh[k4*4+5]*w1.y + sh[k4*4+6]*w1.z + sh[k4*4+7]*w1.w;
            }
            embed[b * EE + tid] = ctrl_b[tid] + sh[tid] + a0 + a1;
        }
    } else {
        // blocks 160..167: firstidx[l][s] — duplicate-merge structure, b-independent
        int lblk = (blk - 160) * 2;            // covers l = lblk, lblk+1
        shi[tid] = slot[lblk * SS + tid];      // 2 rows of 128
        __syncthreads();
        int lrow = tid >> 7, s = tid & 127;
        int c = shi[lrow * 128 + s];
        int fi = s;
        for (int s2 = 0; s2 < 128; ++s2) {
            if (shi[lrow * 128 + s2] == c) { fi = s2; break; }
        }
        fidx[(lblk + lrow) * SS + s] = fi;
    }
}

// ================= K2: scores via bf16 MFMA -> scoresT[b][t] =================
__global__ __launch_bounds__(256) void k_scores_mfma(const float* __restrict__ enc,
                                                     const unsigned short* __restrict__ Bs,
                                                     const float* __restrict__ attn_v,
                                                     const float* __restrict__ hW,
                                                     float* __restrict__ scoresT) {
    __shared__ uint4 AbufV[1024];
    __shared__ float scpart[128];
    unsigned char* Abuf = (unsigned char*)AbufV;

    int i0 = blockIdx.x * 32;
    int tid = threadIdx.x;

    const float4* src = (const float4*)(enc + (size_t)i0 * HH);
#pragma unroll
    for (int it = 0; it < 4; ++it) {
        int c = tid + it * 256;
        int row = c >> 5;
        int kc = c & 31;
        float4 f0 = src[c * 2];
        float4 f1 = src[c * 2 + 1];
        unsigned int p0 = f2bf(f0.x) | ((unsigned int)f2bf(f0.y) << 16);
        unsigned int p1 = f2bf(f0.z) | ((unsigned int)f2bf(f0.w) << 16);
        unsigned int p2 = f2bf(f1.x) | ((unsigned int)f2bf(f1.y) << 16);
        unsigned int p3 = f2bf(f1.z) | ((unsigned int)f2bf(f1.w) << 16);
        int addr = (row * 512 + kc * 16) ^ ((row & 7) << 4);
        *(uint4*)(Abuf + addr) = make_uint4(p0, p1, p2, p3);
    }
    __syncthreads();

    int wv = tid >> 6, lane = tid & 63;
    int lrow = lane & 15, q = lane >> 4;

    f32x4 acc[2][4];
#pragma unroll
    for (int rt = 0; rt < 2; ++rt)
#pragma unroll
        for (int ct = 0; ct < 4; ++ct) acc[rt][ct] = (f32x4){0.f, 0.f, 0.f, 0.f};

    const bf16x8* BsV = (const bf16x8*)Bs;
    for (int ks = 0; ks < 8; ++ks) {
        bf16x8 bfr[4];
        const bf16x8* bsrc = BsV + ((size_t)(ks * 16 + wv * 4) * 64 + lane);
#pragma unroll
        for (int ct = 0; ct < 4; ++ct) bfr[ct] = bsrc[ct * 64];
        bf16x8 afr[2];
#pragma unroll
        for (int rt = 0; rt < 2; ++rt) {
            int arow = rt * 16 + lrow;
            int abyte = (arow * 512 + ks * 64 + q * 16) ^ ((arow & 7) << 4);
            afr[rt] = *(const bf16x8*)(Abuf + abyte);
        }
#pragma unroll
        for (int rt = 0; rt < 2; ++rt)
#pragma unroll
            for (int ct = 0; ct < 4; ++ct)
                acc[rt][ct] = __builtin_amdgcn_mfma_f32_16x16x32_bf16(afr[rt], bfr[ct], acc[rt][ct], 0, 0, 0);
    }

    float vvv[4];
#pragma unroll
    for (int ct = 0; ct < 4; ++ct) vvv[ct] = attn_v[wv * 64 + ct * 16 + lrow];

#pragma unroll
    for (int rt = 0; rt < 2; ++rt) {
        float ps[4];
#pragma unroll
        for (int r = 0; r < 4; ++r) {
            int i = i0 + rt * 16 + q * 4 + r;
            int b = i & (BB - 1);
            const float* hwb = hW + (size_t)b * HH + wv * 64 + lrow;
            float s = 0.f;
#pragma unroll
            for (int ct = 0; ct < 4; ++ct)
                s += vvv[ct] * ftanh(acc[rt][ct][r] + hwb[ct * 16]);
#pragma unroll
            for (int off = 1; off < 16; off <<= 1) s += __shfl_xor(s, off, 64);
            ps[r] = s;
        }
        if (lrow == 0) {
#pragma unroll
            for (int r = 0; r < 4; ++r) scpart[wv * 32 + rt * 16 + q * 4 + r] = ps[r];
        }
    }
    __syncthreads();
    if (tid < 32) {
        float s = scpart[tid] + scpart[32 + tid] + scpart[64 + tid] + scpart[96 + tid];
        int i = i0 + tid;                       // i = t*B + b
        scoresT[(i & 63) * TT + (i >> 6)] = s;  // [b][t]
    }
}

// ================= K3a: context partials, 1024 blocks =================
__global__ __launch_bounds__(256) void k_ctx(const float* __restrict__ enc,
                                             const float* __restrict__ scoresT,
                                             float* __restrict__ partial) {
    __shared__ float red[8];
    __shared__ float wloc[32];
    __shared__ __align__(16) float part[1024];
    int bx = blockIdx.x;
    int c = bx >> 6, b = bx & 63;
    int tid = threadIdx.x;
    int lane = tid & 63, wv = tid >> 6;

    float s0 = scoresT[b * TT + 2 * tid];
    float s1 = scoresT[b * TT + 2 * tid + 1];
    float mx = fmaxf(s0, s1);
#pragma unroll
    for (int off = 32; off; off >>= 1) mx = fmaxf(mx, __shfl_xor(mx, off, 64));
    if (lane == 0) red[wv] = mx;
    __syncthreads();
    float m = fmaxf(fmaxf(red[0], red[1]), fmaxf(red[2], red[3]));
    float e0 = expf(s0 - m), e1 = expf(s1 - m);
    float sm = e0 + e1;
#pragma unroll
    for (int off = 32; off; off >>= 1) sm += __shfl_xor(sm, off, 64);
    if (lane == 0) red[4 + wv] = sm;
    __syncthreads();
    float inv = 1.f / (red[4] + red[5] + red[6] + red[7]);
    if (tid < 32) wloc[tid] = expf(scoresT[b * TT + c * 32 + tid] - m) * inv;
    __syncthreads();

    int h4 = tid & 63, g = tid >> 6;
    f32x4 c4 = {0.f, 0.f, 0.f, 0.f};
    f32x4 d4 = {0.f, 0.f, 0.f, 0.f};
    const f32x4* enc4 = (const f32x4*)enc;
    size_t base = ((size_t)(c * 32 + g * 8) * BB + b) * 64 + h4;
#pragma unroll
    for (int i = 0; i < 8; i += 2) {
        float w0 = wloc[g * 8 + i], w1 = wloc[g * 8 + i + 1];
        f32x4 v0 = enc4[base + (size_t)i * BB * 64];
        f32x4 v1 = enc4[base + (size_t)(i + 1) * BB * 64];
        c4.x += w0 * v0.x; c4.y += w0 * v0.y; c4.z += w0 * v0.z; c4.w += w0 * v0.w;
        d4.x += w1 * v1.x; d4.y += w1 * v1.y; d4.z += w1 * v1.z; d4.w += w1 * v1.w;
    }
    c4.x += d4.x; c4.y += d4.y; c4.z += d4.z; c4.w += d4.w;
    *(f32x4*)&part[g * 256 + h4 * 4] = c4;
    __syncthreads();
    if (tid < 64) {
        f32x4 a0 = *(const f32x4*)&part[0 * 256 + tid * 4];
        f32x4 a1 = *(const f32x4*)&part[1 * 256 + tid * 4];
        f32x4 a2 = *(const f32x4*)&part[2 * 256 + tid * 4];
        f32x4 a3 = *(const f32x4*)&part[3 * 256 + tid * 4];
        f32x4 t4;
        t4.x = (a0.x + a1.x) + (a2.x + a3.x);
        t4.y = (a0.y + a1.y) + (a2.y + a3.y);
        t4.z = (a0.z + a1.z) + (a2.z + a3.z);
        t4.w = (a0.w + a1.w) + (a2.w + a3.w);
        *(f32x4*)&partial[((size_t)c * BB + b) * HH + tid * 4] = t4;
    }
}

// ================= K3b: partial-sum + hidden + gen + probas-stats =================
// smem carve (floats): part[1024]@0, fin[640]@1024, hid[256]@1664, genl[128]@1920,
//   red[128]@2048, genacc[2048]@2176, fidxL(int)[2048]@4224. total 6272.
__global__ __launch_bounds__(1024) void k_ffnn(const float* __restrict__ partial,
                                               const float* __restrict__ embed,
                                               const float* __restrict__ last_hidden,
                                               const float* __restrict__ Whid,
                                               const float* __restrict__ bhid,
                                               const float* __restrict__ Wout,
                                               const float* __restrict__ bout,
                                               const int* __restrict__ fidx,
                                               float* __restrict__ out_hidden,
                                               float* __restrict__ gen,
                                               float* __restrict__ pvals,
                                               float* __restrict__ pbase) {
    __shared__ __align__(16) float smem[6272];
    float* part   = smem;
    float* fin    = smem + 1024;
    float* hid    = smem + 1664;
    float* genl   = smem + 1920;
    float* red    = smem + 2048;
    float* genacc = smem + 2176;
    int*   fidxL  = (int*)(smem + 4224);

    int b = blockIdx.x;
    int tid = threadIdx.x;
    int lane = tid & 63, wv = tid >> 6;

    fidxL[tid] = fidx[tid];
    fidxL[tid + 1024] = fidx[tid + 1024];
    genacc[tid] = 0.f;
    genacc[tid + 1024] = 0.f;

    // phase A: sum 16 partials
    {
        int h = tid & 255, pc = tid >> 8;
        float a0 = 0.f, a1 = 0.f;
#pragma unroll
        for (int j = 0; j < 4; j += 2) {
            a0 += partial[((size_t)(pc * 4 + j) * BB + b) * HH + h];
            a1 += partial[((size_t)(pc * 4 + j + 1) * BB + b) * HH + h];
        }
        part[pc * 256 + h] = a0 + a1;
    }
    __syncthreads();
    if (tid < 256) fin[EE + tid] = (part[tid] + part[256 + tid]) + (part[512 + tid] + part[768 + tid]);
    else if (tid < 384) fin[tid - 256] = embed[b * EE + (tid - 256)];
    else if (tid < 640) fin[EE + HH + (tid - 384)] = last_hidden[b * HH + (tid - 384)];
    __syncthreads();

    // phase B: hidden (4-way chain break)
    {
        int o = tid & 255, kh = tid >> 8;
        const f32x4* wrow = (const f32x4*)(Whid + (size_t)o * (2 * HH + EE)) + kh * 40;
        const float* fb = fin + kh * 160;
        float a0 = 0.f, a1 = 0.f, a2 = 0.f, a3 = 0.f;
#pragma unroll
        for (int k4 = 0; k4 < 40; k4 += 4) {
            f32x4 w0 = wrow[k4], w1 = wrow[k4+1], w2 = wrow[k4+2], w3 = wrow[k4+3];
            a0 += fb[k4*4+ 0]*w0.x + fb[k4*4+ 1]*w0.y + fb[k4*4+ 2]*w0.z + fb[k4*4+ 3]*w0.w;
            a1 += fb[k4*4+ 4]*w1.x + fb[k4*4+ 5]*w1.y + fb[k4*4+ 6]*w1.z + fb[k4*4+ 7]*w1.w;
            a2 += fb[k4*4+ 8]*w2.x + fb[k4*4+ 9]*w2.y + fb[k4*4+10]*w2.z + fb[k4*4+11]*w2.w;
            a3 += fb[k4*4+12]*w3.x + fb[k4*4+13]*w3.y + fb[k4*4+14]*w3.z + fb[k4*4+15]*w3.w;
        }
        part[kh * 256 + o] = (a0 + a1) + (a2 + a3);
    }
    __syncthreads();
    if (tid < HH) {
        float hv = fmaxf((part[tid] + part[256 + tid]) + (part[512 + tid] + part[768 + tid]) + bhid[tid], 0.f);
        hid[tid] = hv;
        out_hidden[(size_t)b * HH + tid] = hv;
    }
    __syncthreads();

    // phase C: gen (2-way chain break)
    {
        int o = tid & 127, q8 = tid >> 7;
        const f32x4* wrow = (const f32x4*)(Wout + (size_t)o * HH) + q8 * 8;
        const float* hb = hid + q8 * 32;
        float a0 = 0.f, a1 = 0.f;
#pragma unroll
        for (int k4 = 0; k4 < 8; k4 += 2) {
            f32x4 w0 = wrow[k4], w1 = wrow[k4+1];
            a0 += hb[k4*4+0]*w0.x + hb[k4*4+1]*w0.y + hb[k4*4+2]*w0.z + hb[k4*4+3]*w0.w;
            a1 += hb[k4*4+4]*w1.x + hb[k4*4+5]*w1.y + hb[k4*4+6]*w1.z + hb[k4*4+7]*w1.w;
        }
        part[q8 * 128 + o] = a0 + a1;
    }
    __syncthreads();
    if (tid < SS) {
        float gv = bout[tid];
#pragma unroll
        for (int j = 0; j < 8; ++j) gv += part[j * 128 + tid];
        gv = fmaxf(gv, 0.f);
        genl[tid] = gv;
        gen[(size_t)b * SS + tid] = gv;
    }
    __syncthreads();

    // phase D: probas stats via precomputed firstidx + LDS atomic merge
    {
        int sA = tid & 127, lA = tid >> 7, lB = lA + 8;
        int fiA = fidxL[lA * SS + sA];
        int fiB = fidxL[lB * SS + sA];
        bool fA = (fiA == sA), fB = (fiB == sA);
        float gs = genl[sA];
        atomicAdd(&genacc[lA * SS + fiA], gs);
        atomicAdd(&genacc[lB * SS + fiB], gs);
        __syncthreads();
        float mgA = -0.01f + genacc[lA * SS + sA];
        float mgB = -0.01f + genacc[lB * SS + sA];
        // max over first-occurrence entries only (duplicates share the first's value)
        float mA = fA ? mgA : -3.0e38f;
        float mB = fB ? mgB : -3.0e38f;
#pragma unroll
        for (int off = 32; off; off >>= 1) {
            mA = fmaxf(mA, __shfl_xor(mA, off, 64));
            mB = fmaxf(mB, __shfl_xor(mB, off, 64));
        }
        if (lane == 0) { red[wv] = mA; red[16 + wv] = mB; }
        __syncthreads();
        float MA = fmaxf(red[2 * lA], red[2 * lA + 1]);
        float MB = fmaxf(red[16 + 2 * lA], red[16 + 2 * lA + 1]);
        float eA = fA ? expf(mgA - MA) : 0.f;
        float eB = fB ? expf(mgB - MB) : 0.f;
        float cA = fA ? 1.f : 0.f, cB = fB ? 1.f : 0.f;
        float s1 = eA, s2v = cA, s3 = eB, s4 = cB;
#pragma unroll
        for (int off = 32; off; off >>= 1) {
            s1 += __shfl_xor(s1, off, 64);
            s2v += __shfl_xor(s2v, off, 64);
            s3 += __shfl_xor(s3, off, 64);
            s4 += __shfl_xor(s4, off, 64);
        }
        if (lane == 0) { red[32 + wv] = s1; red[48 + wv] = s2v; red[64 + wv] = s3; red[80 + wv] = s4; }
        __syncthreads();
        float sumA = red[32 + 2 * lA] + red[32 + 2 * lA + 1];
        float cntA = red[48 + 2 * lA] + red[48 + 2 * lA + 1];
        float sumB = red[64 + 2 * lA] + red[64 + 2 * lA + 1];
        float cntB = red[80 + 2 * lA] + red[80 + 2 * lA + 1];
        float baseA = expf(-0.01f - MA);
        float invA = 1.f / (((float)VV - cntA) * baseA + sumA);
        float baseB = expf(-0.01f - MB);
        float invB = 1.f / (((float)VV - cntB) * baseB + sumB);
        pvals[((size_t)b * LL + lA) * SS + sA] = fA ? eA * invA : -1.f;
        pvals[((size_t)b * LL + lB) * SS + sA] = fB ? eB * invB : -1.f;
        if (sA == 0) {
            pbase[b * LL + lA] = baseA * invA;
            pbase[b * LL + lB] = baseB * invB;
        }
    }
}

// ================= K4: streaming fill + scatter, half-rows =================
__global__ __launch_bounds__(256) void k_fill(const int* __restrict__ slot,
                                              const float* __restrict__ pvals,
                                              const float* __restrict__ pbase,
                                              float* __restrict__ out) {
    int bx = blockIdx.x;
    int row = bx >> 1, half = bx & 1;
    int l = row >> 6, b = row & 63;
    int tid = threadIdx.x;
    __shared__ float pv[SS];
    __shared__ int cls[SS];
    if (tid < SS) {
        pv[tid] = pvals[((size_t)b * LL + l) * SS + tid];
        cls[tid] = slot[l * SS + tid];
    }
    float pb = pbase[b * LL + l];
    float* rowp = out + BB * HH + ((size_t)(l * BB + b)) * VV;
    float4 p4 = make_float4(pb, pb, pb, pb);
    float4* row4 = (float4*)rowp + half * (VV / 8);
#pragma unroll 4
    for (int idx = tid; idx < VV / 8; idx += 256) row4[idx] = p4;
    __syncthreads();
    if (tid < SS && pv[tid] >= 0.f) {
        int c = cls[tid];
        int lo = half * (VV / 2);
        if (c >= lo && c < lo + VV / 2) rowp[c] = pv[tid];
    }
}

extern "C" void kernel_launch(void* const* d_in, const int* in_sizes, int n_in,
                              void* d_out, int out_size, void* d_ws, size_t ws_size,
                              hipStream_t stream) {
    const float* u_enc       = (const float*)d_in[0];
    const float* last_hidden = (const float*)d_in[1];
    const int*   z_tm1       = (const int*)d_in[2];
    const int*   slot        = (const int*)d_in[3];
    const float* emb_W       = (const float*)d_in[4];
    const float* ctrl_W      = (const float*)d_in[5];
    const float* ctrl_b      = (const float*)d_in[6];
    const float* attn_W      = (const float*)d_in[7];
    const float* attn_b      = (const float*)d_in[8];
    const float* attn_v      = (const float*)d_in[9];
    const float* Whid        = (const float*)d_in[10];
    const float* bhid        = (const float*)d_in[11];
    const float* Wout        = (const float*)d_in[12];
    const float* bout        = (const float*)d_in[13];
    float* out = (float*)d_out;
    float* ws = (float*)d_ws;

    float* scoresT = ws;             // 32768 ([b][t])
    float* hW      = ws + 32768;     // 16384
    float* embed   = ws + 49152;     // 8192
    float* gen     = ws + 57344;     // 8192
    unsigned short* Bs = (unsigned short*)(ws + 65536);  // 65536 bf16
    float* pvals   = ws + 98304;     // 131072
    float* pbase   = ws + 229376;    // 1024
    float* partial = ws + 230400;    // 262144
    int*   fidx    = (int*)(ws + 492544);  // 2048 ints

    k_pre<<<168, 256, 0, stream>>>(last_hidden, attn_W, attn_b, z_tm1, emb_W, ctrl_W,
                                   ctrl_b, slot, hW, embed, Bs, fidx);
    k_scores_mfma<<<(TT * BB) / 32, 256, 0, stream>>>(u_enc, Bs, attn_v, hW, scoresT);
    k_ctx<<<16 * BB, 256, 0, stream>>>(u_enc, scoresT, partial);
    k_ffnn<<<BB, 1024, 0, stream>>>(partial, embed, last_hidden, Whid, bhid,
                                    Wout, bout, fidx, out, gen, pvals, pbase);
    k_fill<<<LL * BB * 2, 256, 0, stream>>>(slot, pvals, pbase, out);
}

// Round 10
// 88.990 us; speedup vs baseline: 24.8059x; 1.0032x over previous
//
#include <hip/hip_runtime.h>
#include <hip/hip_bf16.h>

#define BB 64
#define TT 512
#define HH 256
#define EE 128
#define VV 32000
#define SS 128
#define LL 16

typedef __attribute__((ext_vector_type(8))) short bf16x8;
typedef __attribute__((ext_vector_type(4))) float f32x4;

static __device__ __forceinline__ unsigned short f2bf(float x) {
    unsigned int u = __float_as_uint(x);
    unsigned int r = (u + 0x7fffu + ((u >> 16) & 1u)) >> 16;
    return (unsigned short)r;
}

// tanh(x) = 1 - 2/(exp2(x*2*log2e)+1)
static __device__ __forceinline__ float ftanh(float x) {
    float y = __builtin_amdgcn_exp2f(x * 2.885390082f);
    return 1.f - 2.f * __builtin_amdgcn_rcpf(y + 1.f);
}

// ================= K1: {hW, prep_b, embed, slot-firstidx} by blockIdx =================
__global__ __launch_bounds__(256) void k_pre(const float* __restrict__ last_hidden,
                                             const float* __restrict__ attn_W,
                                             const float* __restrict__ attn_b,
                                             const int* __restrict__ z_tm1,
                                             const float* __restrict__ emb_W,
                                             const float* __restrict__ ctrl_W,
                                             const float* __restrict__ ctrl_b,
                                             const int* __restrict__ slot,
                                             float* __restrict__ hW,
                                             float* __restrict__ embed,
                                             unsigned short* __restrict__ Bs,
                                             int* __restrict__ fidx) {
    __shared__ float sh[HH];
    __shared__ int shi[256];
    int blk = blockIdx.x;
    int tid = threadIdx.x;
    if (blk < 64) {
        int b = blk, h = tid;
        sh[h] = last_hidden[b * HH + h];
        __syncthreads();
        const float4* wrow = (const float4*)(attn_W + (size_t)h * (2 * HH));
        float a0 = 0.f, a1 = 0.f, a2 = 0.f, a3 = 0.f;
        for (int k4 = 0; k4 < HH / 4; k4 += 4) {
            float4 w0 = wrow[k4], w1 = wrow[k4+1], w2 = wrow[k4+2], w3 = wrow[k4+3];
            a0 += sh[k4*4+ 0]*w0.x + sh[k4*4+ 1]*w0.y + sh[k4*4+ 2]*w0.z + sh[k4*4+ 3]*w0.w;
            a1 += sh[k4*4+ 4]*w1.x + sh[k4*4+ 5]*w1.y + sh[k4*4+ 6]*w1.z + sh[k4*4+ 7]*w1.w;
            a2 += sh[k4*4+ 8]*w2.x + sh[k4*4+ 9]*w2.y + sh[k4*4+10]*w2.z + sh[k4*4+11]*w2.w;
            a3 += sh[k4*4+12]*w3.x + sh[k4*4+13]*w3.y + sh[k4*4+14]*w3.z + sh[k4*4+15]*w3.w;
        }
        hW[b * HH + h] = attn_b[h] + ((a0 + a1) + (a2 + a3));
    } else if (blk < 96) {
        // Bs layout: [kstep 0..7][tile 0..15][lane 0..63][8 bf16]
        int idx = (blk - 64) * 256 + tid;  // 8192 total
        int lane = idx & 63;
        int gt = (idx >> 6) & 15;
        int ks = idx >> 10;
        int col = gt * 16 + (lane & 15);
        int k0 = ks * 32 + (lane >> 4) * 8;
        const float* src = attn_W + (size_t)col * (2 * HH) + HH + k0;
        unsigned int p0 = f2bf(src[0]) | ((unsigned int)f2bf(src[1]) << 16);
        unsigned int p1 = f2bf(src[2]) | ((unsigned int)f2bf(src[3]) << 16);
        unsigned int p2 = f2bf(src[4]) | ((unsigned int)f2bf(src[5]) << 16);
        unsigned int p3 = f2bf(src[6]) | ((unsigned int)f2bf(src[7]) << 16);
        *(uint4*)(Bs + (size_t)idx * 8) = make_uint4(p0, p1, p2, p3);
    } else if (blk < 160) {
        int b = blk - 96;
        if (tid < EE) sh[tid] = emb_W[(size_t)z_tm1[b] * EE + tid];
        __syncthreads();
        if (tid < EE) {
            const float4* wrow = (const float4*)(ctrl_W + (size_t)tid * EE);
            float a0 = 0.f, a1 = 0.f;
            for (int k4 = 0; k4 < EE / 4; k4 += 2) {
                float4 w0 = wrow[k4], w1 = wrow[k4+1];
                a0 += sh[k4*4+0]*w0.x + sh[k4*4+1]*w0.y + sh[k4*4+2]*w0.z + sh[k4*4+3]*w0.w;
                a1 += sh[k4*4+4]*w1.x + sh[k4*4+5]*w1.y + sh[k4*4+6]*w1.z + sh[k4*4+7]*w1.w;
            }
            embed[b * EE + tid] = ctrl_b[tid] + sh[tid] + a0 + a1;
        }
    } else {
        // blocks 160..167: firstidx[l][s] — duplicate-merge structure, b-independent
        int lblk = (blk - 160) * 2;            // covers l = lblk, lblk+1
        shi[tid] = slot[lblk * SS + tid];      // 2 rows of 128
        __syncthreads();
        int lrow = tid >> 7, s = tid & 127;
        int c = shi[lrow * 128 + s];
        int fi = s;
        for (int s2 = 0; s2 < 128; ++s2) {
            if (shi[lrow * 128 + s2] == c) { fi = s2; break; }
        }
        fidx[(lblk + lrow) * SS + s] = fi;
    }
}

// ================= K2: scores via bf16 MFMA -> scoresT[b][t] =================
__global__ __launch_bounds__(256) void k_scores_mfma(const float* __restrict__ enc,
                                                     const unsigned short* __restrict__ Bs,
                                                     const float* __restrict__ attn_v,
                                                     const float* __restrict__ hW,
                                                     float* __restrict__ scoresT) {
    __shared__ uint4 AbufV[1024];
    __shared__ float scpart[128];
    unsigned char* Abuf = (unsigned char*)AbufV;

    int i0 = blockIdx.x * 32;
    int tid = threadIdx.x;

    const float4* src = (const float4*)(enc + (size_t)i0 * HH);
#pragma unroll
    for (int it = 0; it < 4; ++it) {
        int c = tid + it * 256;
        int row = c >> 5;
        int kc = c & 31;
        float4 f0 = src[c * 2];
        float4 f1 = src[c * 2 + 1];
        unsigned int p0 = f2bf(f0.x) | ((unsigned int)f2bf(f0.y) << 16);
        unsigned int p1 = f2bf(f0.z) | ((unsigned int)f2bf(f0.w) << 16);
        unsigned int p2 = f2bf(f1.x) | ((unsigned int)f2bf(f1.y) << 16);
        unsigned int p3 = f2bf(f1.z) | ((unsigned int)f2bf(f1.w) << 16);
        int addr = (row * 512 + kc * 16) ^ ((row & 7) << 4);
        *(uint4*)(Abuf + addr) = make_uint4(p0, p1, p2, p3);
    }
    __syncthreads();

    int wv = tid >> 6, lane = tid & 63;
    int lrow = lane & 15, q = lane >> 4;

    f32x4 acc[2][4];
#pragma unroll
    for (int rt = 0; rt < 2; ++rt)
#pragma unroll
        for (int ct = 0; ct < 4; ++ct) acc[rt][ct] = (f32x4){0.f, 0.f, 0.f, 0.f};

    const bf16x8* BsV = (const bf16x8*)Bs;
    for (int ks = 0; ks < 8; ++ks) {
        bf16x8 bfr[4];
        const bf16x8* bsrc = BsV + ((size_t)(ks * 16 + wv * 4) * 64 + lane);
#pragma unroll
        for (int ct = 0; ct < 4; ++ct) bfr[ct] = bsrc[ct * 64];
        bf16x8 afr[2];
#pragma unroll
        for (int rt = 0; rt < 2; ++rt) {
            int arow = rt * 16 + lrow;
            int abyte = (arow * 512 + ks * 64 + q * 16) ^ ((arow & 7) << 4);
            afr[rt] = *(const bf16x8*)(Abuf + abyte);
        }
#pragma unroll
        for (int rt = 0; rt < 2; ++rt)
#pragma unroll
            for (int ct = 0; ct < 4; ++ct)
                acc[rt][ct] = __builtin_amdgcn_mfma_f32_16x16x32_bf16(afr[rt], bfr[ct], acc[rt][ct], 0, 0, 0);
    }

    float vvv[4];
#pragma unroll
    for (int ct = 0; ct < 4; ++ct) vvv[ct] = attn_v[wv * 64 + ct * 16 + lrow];

#pragma unroll
    for (int rt = 0; rt < 2; ++rt) {
        float ps[4];
#pragma unroll
        for (int r = 0; r < 4; ++r) {
            int i = i0 + rt * 16 + q * 4 + r;
            int b = i & (BB - 1);
            const float* hwb = hW + (size_t)b * HH + wv * 64 + lrow;
            float s = 0.f;
#pragma unroll
            for (int ct = 0; ct < 4; ++ct)
                s += vvv[ct] * ftanh(acc[rt][ct][r] + hwb[ct * 16]);
#pragma unroll
            for (int off = 1; off < 16; off <<= 1) s += __shfl_xor(s, off, 64);
            ps[r] = s;
        }
        if (lrow == 0) {
#pragma unroll
            for (int r = 0; r < 4; ++r) scpart[wv * 32 + rt * 16 + q * 4 + r] = ps[r];
        }
    }
    __syncthreads();
    if (tid < 32) {
        float s = scpart[tid] + scpart[32 + tid] + scpart[64 + tid] + scpart[96 + tid];
        int i = i0 + tid;                       // i = t*B + b
        scoresT[(i & 63) * TT + (i >> 6)] = s;  // [b][t]
    }
}

// ================= K3a: context partials, 1024 blocks =================
__global__ __launch_bounds__(256) void k_ctx(const float* __restrict__ enc,
                                             const float* __restrict__ scoresT,
                                             float* __restrict__ partial) {
    __shared__ float red[8];
    __shared__ float wloc[32];
    __shared__ __align__(16) float part[1024];
    int bx = blockIdx.x;
    int c = bx >> 6, b = bx & 63;
    int tid = threadIdx.x;
    int lane = tid & 63, wv = tid >> 6;

    float s0 = scoresT[b * TT + 2 * tid];
    float s1 = scoresT[b * TT + 2 * tid + 1];
    float mx = fmaxf(s0, s1);
#pragma unroll
    for (int off = 32; off; off >>= 1) mx = fmaxf(mx, __shfl_xor(mx, off, 64));
    if (lane == 0) red[wv] = mx;
    __syncthreads();
    float m = fmaxf(fmaxf(red[0], red[1]), fmaxf(red[2], red[3]));
    float e0 = expf(s0 - m), e1 = expf(s1 - m);
    float sm = e0 + e1;
#pragma unroll
    for (int off = 32; off; off >>= 1) sm += __shfl_xor(sm, off, 64);
    if (lane == 0) red[4 + wv] = sm;
    __syncthreads();
    float inv = 1.f / (red[4] + red[5] + red[6] + red[7]);
    if (tid < 32) wloc[tid] = expf(scoresT[b * TT + c * 32 + tid] - m) * inv;
    __syncthreads();

    int h4 = tid & 63, g = tid >> 6;
    f32x4 c4 = {0.f, 0.f, 0.f, 0.f};
    f32x4 d4 = {0.f, 0.f, 0.f, 0.f};
    const f32x4* enc4 = (const f32x4*)enc;
    size_t base = ((size_t)(c * 32 + g * 8) * BB + b) * 64 + h4;
#pragma unroll
    for (int i = 0; i < 8; i += 2) {
        float w0 = wloc[g * 8 + i], w1 = wloc[g * 8 + i + 1];
        f32x4 v0 = enc4[base + (size_t)i * BB * 64];
        f32x4 v1 = enc4[base + (size_t)(i + 1) * BB * 64];
        c4.x += w0 * v0.x; c4.y += w0 * v0.y; c4.z += w0 * v0.z; c4.w += w0 * v0.w;
        d4.x += w1 * v1.x; d4.y += w1 * v1.y; d4.z += w1 * v1.z; d4.w += w1 * v1.w;
    }
    c4.x += d4.x; c4.y += d4.y; c4.z += d4.z; c4.w += d4.w;
    *(f32x4*)&part[g * 256 + h4 * 4] = c4;
    __syncthreads();
    if (tid < 64) {
        f32x4 a0 = *(const f32x4*)&part[0 * 256 + tid * 4];
        f32x4 a1 = *(const f32x4*)&part[1 * 256 + tid * 4];
        f32x4 a2 = *(const f32x4*)&part[2 * 256 + tid * 4];
        f32x4 a3 = *(const f32x4*)&part[3 * 256 + tid * 4];
        f32x4 t4;
        t4.x = (a0.x + a1.x) + (a2.x + a3.x);
        t4.y = (a0.y + a1.y) + (a2.y + a3.y);
        t4.z = (a0.z + a1.z) + (a2.z + a3.z);
        t4.w = (a0.w + a1.w) + (a2.w + a3.w);
        *(f32x4*)&partial[((size_t)c * BB + b) * HH + tid * 4] = t4;
    }
}

// ================= K3b: partial-sum + hidden + gen + probas-stats =================
// smem carve (floats): part[1024]@0, fin[640]@1024, hid[256]@1664, genl[128]@1920,
//   red[128]@2048, genacc[2048]@2176, fidxL(int)[2048]@4224. total 6272.
__global__ __launch_bounds__(1024) void k_ffnn(const float* __restrict__ partial,
                                               const float* __restrict__ embed,
                                               const float* __restrict__ last_hidden,
                                               const float* __restrict__ Whid,
                                               const float* __restrict__ bhid,
                                               const float* __restrict__ Wout,
                                               const float* __restrict__ bout,
                                               const int* __restrict__ fidx,
                                               float* __restrict__ out_hidden,
                                               float* __restrict__ gen,
                                               float* __restrict__ pvals,
                                               float* __restrict__ pbase) {
    __shared__ __align__(16) float smem[6272];
    float* part   = smem;
    float* fin    = smem + 1024;
    float* hid    = smem + 1664;
    float* genl   = smem + 1920;
    float* red    = smem + 2048;
    float* genacc = smem + 2176;
    int*   fidxL  = (int*)(smem + 4224);

    int b = blockIdx.x;
    int tid = threadIdx.x;
    int lane = tid & 63, wv = tid >> 6;

    fidxL[tid] = fidx[tid];
    fidxL[tid + 1024] = fidx[tid + 1024];
    genacc[tid] = 0.f;
    genacc[tid + 1024] = 0.f;

    // phase A: sum 16 partials
    {
        int h = tid & 255, pc = tid >> 8;
        float a0 = 0.f, a1 = 0.f;
#pragma unroll
        for (int j = 0; j < 4; j += 2) {
            a0 += partial[((size_t)(pc * 4 + j) * BB + b) * HH + h];
            a1 += partial[((size_t)(pc * 4 + j + 1) * BB + b) * HH + h];
        }
        part[pc * 256 + h] = a0 + a1;
    }
    __syncthreads();
    if (tid < 256) fin[EE + tid] = (part[tid] + part[256 + tid]) + (part[512 + tid] + part[768 + tid]);
    else if (tid < 384) fin[tid - 256] = embed[b * EE + (tid - 256)];
    else if (tid < 640) fin[EE + HH + (tid - 384)] = last_hidden[b * HH + (tid - 384)];
    __syncthreads();

    // phase B: hidden (4-way chain break)
    {
        int o = tid & 255, kh = tid >> 8;
        const f32x4* wrow = (const f32x4*)(Whid + (size_t)o * (2 * HH + EE)) + kh * 40;
        const float* fb = fin + kh * 160;
        float a0 = 0.f, a1 = 0.f, a2 = 0.f, a3 = 0.f;
#pragma unroll
        for (int k4 = 0; k4 < 40; k4 += 4) {
            f32x4 w0 = wrow[k4], w1 = wrow[k4+1], w2 = wrow[k4+2], w3 = wrow[k4+3];
            a0 += fb[k4*4+ 0]*w0.x + fb[k4*4+ 1]*w0.y + fb[k4*4+ 2]*w0.z + fb[k4*4+ 3]*w0.w;
            a1 += fb[k4*4+ 4]*w1.x + fb[k4*4+ 5]*w1.y + fb[k4*4+ 6]*w1.z + fb[k4*4+ 7]*w1.w;
            a2 += fb[k4*4+ 8]*w2.x + fb[k4*4+ 9]*w2.y + fb[k4*4+10]*w2.z + fb[k4*4+11]*w2.w;
            a3 += fb[k4*4+12]*w3.x + fb[k4*4+13]*w3.y + fb[k4*4+14]*w3.z + fb[k4*4+15]*w3.w;
        }
        part[kh * 256 + o] = (a0 + a1) + (a2 + a3);
    }
    __syncthreads();
    if (tid < HH) {
        float hv = fmaxf((part[tid] + part[256 + tid]) + (part[512 + tid] + part[768 + tid]) + bhid[tid], 0.f);
        hid[tid] = hv;
        out_hidden[(size_t)b * HH + tid] = hv;
    }
    __syncthreads();

    // phase C: gen (2-way chain break)
    {
        int o = tid & 127, q8 = tid >> 7;
        const f32x4* wrow = (const f32x4*)(Wout + (size_t)o * HH) + q8 * 8;
        const float* hb = hid + q8 * 32;
        float a0 = 0.f, a1 = 0.f;
#pragma unroll
        for (int k4 = 0; k4 < 8; k4 += 2) {
            f32x4 w0 = wrow[k4], w1 = wrow[k4+1];
            a0 += hb[k4*4+0]*w0.x + hb[k4*4+1]*w0.y + hb[k4*4+2]*w0.z + hb[k4*4+3]*w0.w;
            a1 += hb[k4*4+4]*w1.x + hb[k4*4+5]*w1.y + hb[k4*4+6]*w1.z + hb[k4*4+7]*w1.w;
        }
        part[q8 * 128 + o] = a0 + a1;
    }
    __syncthreads();
    if (tid < SS) {
        float gv = bout[tid];
#pragma unroll
        for (int j = 0; j < 8; ++j) gv += part[j * 128 + tid];
        gv = fmaxf(gv, 0.f);
        genl[tid] = gv;
        gen[(size_t)b * SS + tid] = gv;
    }
    __syncthreads();

    // phase D: probas stats via precomputed firstidx + LDS atomic merge
    {
        int sA = tid & 127, lA = tid >> 7, lB = lA + 8;
        int fiA = fidxL[lA * SS + sA];
        int fiB = fidxL[lB * SS + sA];
        bool fA = (fiA == sA), fB = (fiB == sA);
        float gs = genl[sA];
        atomicAdd(&genacc[lA * SS + fiA], gs);
        atomicAdd(&genacc[lB * SS + fiB], gs);
        __syncthreads();
        float mgA = -0.01f + genacc[lA * SS + sA];
        float mgB = -0.01f + genacc[lB * SS + sA];
        // max over first-occurrence entries only (duplicates share the first's value)
        float mA = fA ? mgA : -3.0e38f;
        float mB = fB ? mgB : -3.0e38f;
#pragma unroll
        for (int off = 32; off; off >>= 1) {
            mA = fmaxf(mA, __shfl_xor(mA, off, 64));
            mB = fmaxf(mB, __shfl_xor(mB, off, 64));
        }
        if (lane == 0) { red[wv] = mA; red[16 + wv] = mB; }
        __syncthreads();
        float MA = fmaxf(red[2 * lA], red[2 * lA + 1]);
        float MB = fmaxf(red[16 + 2 * lA], red[16 + 2 * lA + 1]);
        float eA = fA ? expf(mgA - MA) : 0.f;
        float eB = fB ? expf(mgB - MB) : 0.f;
        float cA = fA ? 1.f : 0.f, cB = fB ? 1.f : 0.f;
        float s1 = eA, s2v = cA, s3 = eB, s4 = cB;
#pragma unroll
        for (int off = 32; off; off >>= 1) {
            s1 += __shfl_xor(s1, off, 64);
            s2v += __shfl_xor(s2v, off, 64);
            s3 += __shfl_xor(s3, off, 64);
            s4 += __shfl_xor(s4, off, 64);
        }
        if (lane == 0) { red[32 + wv] = s1; red[48 + wv] = s2v; red[64 + wv] = s3; red[80 + wv] = s4; }
        __syncthreads();
        float sumA = red[32 + 2 * lA] + red[32 + 2 * lA + 1];
        float cntA = red[48 + 2 * lA] + red[48 + 2 * lA + 1];
        float sumB = red[64 + 2 * lA] + red[64 + 2 * lA + 1];
        float cntB = red[80 + 2 * lA] + red[80 + 2 * lA + 1];
        float baseA = expf(-0.01f - MA);
        float invA = 1.f / (((float)VV - cntA) * baseA + sumA);
        float baseB = expf(-0.01f - MB);
        float invB = 1.f / (((float)VV - cntB) * baseB + sumB);
        pvals[((size_t)b * LL + lA) * SS + sA] = fA ? eA * invA : -1.f;
        pvals[((size_t)b * LL + lB) * SS + sA] = fB ? eB * invB : -1.f;
        if (sA == 0) {
            pbase[b * LL + lA] = baseA * invA;
            pbase[b * LL + lB] = baseB * invB;
        }
    }
}

// ================= K4: streaming fill + scatter, half-rows =================
__global__ __launch_bounds__(256) void k_fill(const int* __restrict__ slot,
                                              const float* __restrict__ pvals,
                                              const float* __restrict__ pbase,
                                              float* __restrict__ out) {
    int bx = blockIdx.x;
    int row = bx >> 1, half = bx & 1;
    int l = row >> 6, b = row & 63;
    int tid = threadIdx.x;
    __shared__ float pv[SS];
    __shared__ int cls[SS];
    if (tid < SS) {
        pv[tid] = pvals[((size_t)b * LL + l) * SS + tid];
        cls[tid] = slot[l * SS + tid];
    }
    float pb = pbase[b * LL + l];
    float* rowp = out + BB * HH + ((size_t)(l * BB + b)) * VV;
    float4 p4 = make_float4(pb, pb, pb, pb);
    float4* row4 = (float4*)rowp + half * (VV / 8);
#pragma unroll 4
    for (int idx = tid; idx < VV / 8; idx += 256) row4[idx] = p4;
    __syncthreads();
    if (tid < SS && pv[tid] >= 0.f) {
        int c = cls[tid];
        int lo = half * (VV / 2);
        if (c >= lo && c < lo + VV / 2) rowp[c] = pv[tid];
    }
}

extern "C" void kernel_launch(void* const* d_in, const int* in_sizes, int n_in,
                              void* d_out, int out_size, void* d_ws, size_t ws_size,
                              hipStream_t stream) {
    const float* u_enc       = (const float*)d_in[0];
    const float* last_hidden = (const float*)d_in[1];
    const int*   z_tm1       = (const int*)d_in[2];
    const int*   slot        = (const int*)d_in[3];
    const float* emb_W       = (const float*)d_in[4];
    const float* ctrl_W      = (const float*)d_in[5];
    const float* ctrl_b      = (const float*)d_in[6];
    const float* attn_W      = (const float*)d_in[7];
    const float* attn_b      = (const float*)d_in[8];
    const float* attn_v      = (const float*)d_in[9];
    const float* Whid        = (const float*)d_in[10];
    const float* bhid        = (const float*)d_in[11];
    const float* Wout        = (const float*)d_in[12];
    const float* bout        = (const float*)d_in[13];
    float* out = (float*)d_out;
    float* ws = (float*)d_ws;

    float* scoresT = ws;             // 32768 ([b][t])
    float* hW      = ws + 32768;     // 16384
    float* embed   = ws + 49152;     // 8192
    float* gen     = ws + 57344;     // 8192
    unsigned short* Bs = (unsigned short*)(ws + 65536);  // 65536 bf16
    float* pvals   = ws + 98304;     // 131072
    float* pbase   = ws + 229376;    // 1024
    float* partial = ws + 230400;    // 262144
    int*   fidx    = (int*)(ws + 492544);  // 2048 ints

    k_pre<<<168, 256, 0, stream>>>(last_hidden, attn_W, attn_b, z_tm1, emb_W, ctrl_W,
                                   ctrl_b, slot, hW, embed, Bs, fidx);
    k_scores_mfma<<<(TT * BB) / 32, 256, 0, stream>>>(u_enc, Bs, attn_v, hW, scoresT);
    k_ctx<<<16 * BB, 256, 0, stream>>>(u_enc, scoresT, partial);
    k_ffnn<<<BB, 1024, 0, stream>>>(partial, embed, last_hidden, Whid, bhid,
                                    Wout, bout, fidx, out, gen, pvals, pbase);
    k_fill<<<LL * BB * 2, 256, 0, stream>>>(slot, pvals, pbase, out);
}